// Round 1
// 3495.834 us; speedup vs baseline: 6.4188x; 6.4188x over previous
//
#include <hip/hip_runtime.h>
#include <hip/hip_bf16.h>
#include <stdint.h>

// Problem dims
#define TT 512
#define BB 128
#define ESEQ 768
#define CONDD 256
#define HH 1024
#define G3 3072

typedef __attribute__((ext_vector_type(4))) float f32x4;
typedef __attribute__((ext_vector_type(8))) short bf16x8;

__device__ __forceinline__ unsigned short f2bf(float f) {
  union { float f; uint32_t u; } v; v.f = f;
  uint32_t r = v.u + 0x7fffu + ((v.u >> 16) & 1u);
  return (unsigned short)(r >> 16);
}
__device__ __forceinline__ float bf2f(uint32_t b16) {
  union { uint32_t u; float f; } v; v.u = (b16 & 0xffffu) << 16;
  return v.f;
}

// ---------------- W_hh fp32 -> bf16 (packed pairs) ----------------
__global__ __launch_bounds__(256) void k_cvt_whh(const float* __restrict__ w,
                                                 uint32_t* __restrict__ o) {
  int i = blockIdx.x * 256 + threadIdx.x;  // pair index, n/2 = 1572864
  const float2* s = (const float2*)w;
  float2 v = s[i];
  o[i] = (uint32_t)f2bf(v.x) | ((uint32_t)f2bf(v.y) << 16);
}

// ---------------- wordgate[b,g] = word[b,:] . W_ih[g,:256] + b_ih[g] (+ b_hh r/z) --------
__global__ __launch_bounds__(128) void k_wordgate(const float* __restrict__ word,
                                                  const float* __restrict__ Wih,
                                                  const float* __restrict__ bih,
                                                  const float* __restrict__ bhh,
                                                  float* __restrict__ wg) {
  __shared__ float wrow[CONDD];
  int g = blockIdx.x;
  for (int e = threadIdx.x; e < CONDD; e += 128) wrow[e] = Wih[(size_t)g * 1024 + e];
  __syncthreads();
  int b = threadIdx.x;
  float bias = bih[g] + (g < 2048 ? bhh[g] : 0.f);  // b_hh new-gate part handled in scan
  const f32x4* wr4 = (const f32x4*)(word + (size_t)b * CONDD);
  const f32x4* wo4 = (const f32x4*)wrow;
  float s = 0.f;
#pragma unroll 8
  for (int e = 0; e < CONDD / 4; e++) {
    f32x4 a = wr4[e], c = wo4[e];
    s += a.x * c.x + a.y * c.y + a.z * c.z + a.w * c.w;
  }
  wg[(size_t)b * G3 + g] = s + bias;
}

// ---------------- gx GEMM: [65536 x 768] * [3072 x 768]^T -> bf16 gx ----------------
// 128x128 tile, BK=64, 4 waves each computing 64x64 via 4x4 of 16x16x32 MFMA.
__global__ __launch_bounds__(256) void k_gemm_gx(const float* __restrict__ seq,
                                                 const float* __restrict__ Wih,
                                                 const float* __restrict__ wg,
                                                 unsigned short* __restrict__ gx) {
  __shared__ unsigned short lA[128 * 72];  // pad 64->72 elems (144B rows: 2-way only)
  __shared__ unsigned short lB[128 * 72];
  int bx = blockIdx.x;
  int m0 = (bx / 24) * 128;
  int n0 = (bx % 24) * 128;
  int tid = threadIdx.x;
  int lane = tid & 63, w = tid >> 6;
  int mw = w & 1, nw = w >> 1;
  int fr = lane & 15, kq = lane >> 4;

  f32x4 acc[4][4];
#pragma unroll
  for (int i = 0; i < 4; i++)
#pragma unroll
    for (int j = 0; j < 4; j++) acc[i][j] = (f32x4){0.f, 0.f, 0.f, 0.f};

  int r = tid >> 1, hf = tid & 1;
  const float* aptr = seq + (size_t)(m0 + r) * ESEQ + hf * 32;
  const float* bptr = Wih + (size_t)(n0 + r) * 1024 + CONDD + hf * 32;
  unsigned short* lAw = lA + r * 72 + hf * 32;
  unsigned short* lBw = lB + r * 72 + hf * 32;

  for (int kk = 0; kk < ESEQ / 64; kk++) {
#pragma unroll
    for (int q = 0; q < 4; q++) {
      f32x4 a0 = *(const f32x4*)(aptr + kk * 64 + q * 8);
      f32x4 a1 = *(const f32x4*)(aptr + kk * 64 + q * 8 + 4);
      f32x4 b0 = *(const f32x4*)(bptr + kk * 64 + q * 8);
      f32x4 b1 = *(const f32x4*)(bptr + kk * 64 + q * 8 + 4);
      union { bf16x8 v; unsigned short s[8]; } pa, pb;
      pa.s[0] = f2bf(a0.x); pa.s[1] = f2bf(a0.y); pa.s[2] = f2bf(a0.z); pa.s[3] = f2bf(a0.w);
      pa.s[4] = f2bf(a1.x); pa.s[5] = f2bf(a1.y); pa.s[6] = f2bf(a1.z); pa.s[7] = f2bf(a1.w);
      pb.s[0] = f2bf(b0.x); pb.s[1] = f2bf(b0.y); pb.s[2] = f2bf(b0.z); pb.s[3] = f2bf(b0.w);
      pb.s[4] = f2bf(b1.x); pb.s[5] = f2bf(b1.y); pb.s[6] = f2bf(b1.z); pb.s[7] = f2bf(b1.w);
      *(bf16x8*)(lAw + q * 8) = pa.v;
      *(bf16x8*)(lBw + q * 8) = pb.v;
    }
    __syncthreads();
#pragma unroll
    for (int ks = 0; ks < 2; ks++) {
      bf16x8 af[4], bf[4];
#pragma unroll
      for (int i = 0; i < 4; i++)
        af[i] = *(const bf16x8*)(lA + (mw * 64 + i * 16 + fr) * 72 + ks * 32 + kq * 8);
#pragma unroll
      for (int j = 0; j < 4; j++)
        bf[j] = *(const bf16x8*)(lB + (nw * 64 + j * 16 + fr) * 72 + ks * 32 + kq * 8);
#pragma unroll
      for (int i = 0; i < 4; i++)
#pragma unroll
        for (int j = 0; j < 4; j++)
          acc[i][j] = __builtin_amdgcn_mfma_f32_16x16x32_bf16(af[i], bf[j], acc[i][j], 0, 0, 0);
    }
    __syncthreads();
  }

  // epilogue: C[row][col] : col=lane&15, row=(lane>>4)*4+reg (m89/m91-verified)
#pragma unroll
  for (int i = 0; i < 4; i++) {
#pragma unroll
    for (int j = 0; j < 4; j++) {
      int col = n0 + nw * 64 + j * 16 + fr;
      int rbase = m0 + mw * 64 + i * 16 + kq * 4;
#pragma unroll
      for (int rr = 0; rr < 4; rr++) {
        int row = rbase + rr;
        float v = acc[i][j][rr] + wg[(size_t)(row & (BB - 1)) * G3 + col];
        gx[(size_t)row * G3 + col] = f2bf(v);
      }
    }
  }
}

// ---------------- persistent scan kernel ----------------
// 256 blocks = 8 m-groups (16 batch rows each) x 32 j-chunks (32 h-cols each).
// 6 waves/block: wave = (gate in 0..2, nt in 0..1); W_hh slice held in VGPRs.
//
// Barrier rationale: ALL cross-block data (hb, counters) moves via agent-scope
// ATOMICS, which compile to sc1 cache-bypassing ops hitting the MALL coherence
// point directly. So no acquire/release fences (= buffer_inv / buffer_wbl2 L2
// maintenance, catastrophic when issued per poll iteration) are needed —
// ordering only requires this block's sc1 stores drained (vmcnt 0) before the
// counter increment, which the explicit waitcnt + __syncthreads guarantees.
__device__ __forceinline__ void gbar(int* ctr, int target) {
  asm volatile("s_waitcnt vmcnt(0)" ::: "memory");  // drain this wave's hb stores to MALL
  __syncthreads();  // all waves drained (barrier lowering waits vmcnt(0)) before t0 proceeds
  if (threadIdx.x == 0) {
    __hip_atomic_fetch_add(ctr, 1, __ATOMIC_RELAXED, __HIP_MEMORY_SCOPE_AGENT);
    while (__hip_atomic_load(ctr, __ATOMIC_RELAXED, __HIP_MEMORY_SCOPE_AGENT) < target) {
      __builtin_amdgcn_s_sleep(1);
    }
  }
  __syncthreads();
}

__global__ __launch_bounds__(384, 2) void k_scan(const unsigned short* __restrict__ gx,
                                                 const unsigned short* __restrict__ whhb,
                                                 const float* __restrict__ inith,
                                                 const float* __restrict__ bhh,
                                                 uint32_t* __restrict__ hb,  // [2][65536] bf16-pairs
                                                 int* __restrict__ counters,
                                                 float* __restrict__ out) {
  __shared__ unsigned short lh[16 * 1032];  // A tile, padded rows (2064B stride)
  __shared__ float ghs[3 * 16 * 32];
  __shared__ float h32[16 * 32];

  int bx = blockIdx.x;
  int m = bx & 7, j = bx >> 3;
  int tid = threadIdx.x;
  int lane = tid & 63, w = tid >> 6;
  int gate = w >> 1, nt = w & 1;
  int fr = lane & 15, kq = lane >> 4;
  int* ctr = counters + m * 32;

  // W_hh fragments for this wave's 16 gh-columns, all K=1024, in registers.
  bf16x8 bw[32];
  {
    const bf16x8* wp =
        (const bf16x8*)(whhb + ((size_t)(gate * 1024 + j * 32 + nt * 16 + fr)) * 1024 + kq * 8);
#pragma unroll
    for (int ks = 0; ks < 32; ks++) bw[ks] = wp[ks * 4];
  }

  int er = tid >> 4, ecp = tid & 15;  // elementwise mapping (tid<256): row er, col-pair ecp
  float bhn0 = 0.f, bhn1 = 0.f;
  if (tid < 256) {
    bhn0 = bhh[2048 + j * 32 + ecp * 2];
    bhn1 = bhh[2048 + j * 32 + ecp * 2 + 1];
  }

  // init h state (fp32 slice in LDS; bf16 copy to global buf0)
  if (tid < 256) {
    int brow = m * 16 + er, col = j * 32 + ecp * 2;
    float a = inith[(size_t)brow * HH + col];
    float b = inith[(size_t)brow * HH + col + 1];
    h32[er * 32 + ecp * 2] = a;
    h32[er * 32 + ecp * 2 + 1] = b;
    uint32_t pk = (uint32_t)f2bf(a) | ((uint32_t)f2bf(b) << 16);
    __hip_atomic_store(&hb[((size_t)brow * HH + col) >> 1], pk, __ATOMIC_RELAXED,
                       __HIP_MEMORY_SCOPE_AGENT);
  }
  gbar(ctr, 32);
  int tgt = 32;

  for (int t = 0; t < TT; t++) {
    // prefetch gx for this step (t-dependent only; overlaps with h staging + MFMA)
    uint32_t xru = 0, xzu = 0, xnu = 0;
    if (tid < 256) {
      int brow = m * 16 + er;
      const uint32_t* gxp = (const uint32_t*)(gx + ((size_t)t * BB + brow) * G3 + j * 32);
      xru = gxp[ecp];
      xzu = gxp[512 + ecp];
      xnu = gxp[1024 + ecp];
    }

    // stage h rows [m*16, m*16+16) from buf (t&1): 4096 x 8B, agent-scope (cross-XCD fresh)
    {
      const uint64_t* src = (const uint64_t*)hb + (size_t)(t & 1) * 32768 + (size_t)m * 4096;
      uint64_t tmp[11];
#pragma unroll
      for (int q = 0; q < 11; q++) {
        int i = tid + q * 384;
        if (i < 4096) tmp[q] = __hip_atomic_load(src + i, __ATOMIC_RELAXED, __HIP_MEMORY_SCOPE_AGENT);
      }
#pragma unroll
      for (int q = 0; q < 11; q++) {
        int i = tid + q * 384;
        if (i < 4096) {
          int rr = i >> 8, c4 = i & 255;
          *(uint64_t*)(lh + rr * 1032 + c4 * 4) = tmp[q];
        }
      }
    }
    __syncthreads();

    // gh tile: 16(batch) x 16(cols) for this wave's gate
    f32x4 acc = (f32x4){0.f, 0.f, 0.f, 0.f};
#pragma unroll
    for (int ks = 0; ks < 32; ks++) {
      bf16x8 af = *(const bf16x8*)(lh + fr * 1032 + kq * 8 + ks * 32);
      acc = __builtin_amdgcn_mfma_f32_16x16x32_bf16(af, bw[ks], acc, 0, 0, 0);
    }
#pragma unroll
    for (int rr = 0; rr < 4; rr++)
      ghs[gate * 512 + (kq * 4 + rr) * 32 + nt * 16 + fr] = acc[rr];
    __syncthreads();

    // gates + state update (256 workers: 16 rows x 16 col-pairs)
    if (tid < 256) {
      int brow = m * 16 + er;
      int c0 = ecp * 2;
      float hnew0, hnew1;
      {
        float xr = bf2f(xru), xz = bf2f(xzu), xn = bf2f(xnu);
        float hr = ghs[0 * 512 + er * 32 + c0];
        float hz = ghs[1 * 512 + er * 32 + c0];
        float hn = ghs[2 * 512 + er * 32 + c0] + bhn0;
        float rg = 1.f / (1.f + __expf(-(xr + hr)));
        float zg = 1.f / (1.f + __expf(-(xz + hz)));
        float pre = xn + rg * hn;
        float ng = 1.f - 2.f / (__expf(2.f * pre) + 1.f);
        float hold = h32[er * 32 + c0];
        hnew0 = (1.f - zg) * ng + zg * hold;
        h32[er * 32 + c0] = hnew0;
      }
      {
        float xr = bf2f(xru >> 16), xz = bf2f(xzu >> 16), xn = bf2f(xnu >> 16);
        float hr = ghs[0 * 512 + er * 32 + c0 + 1];
        float hz = ghs[1 * 512 + er * 32 + c0 + 1];
        float hn = ghs[2 * 512 + er * 32 + c0 + 1] + bhn1;
        float rg = 1.f / (1.f + __expf(-(xr + hr)));
        float zg = 1.f / (1.f + __expf(-(xz + hz)));
        float pre = xn + rg * hn;
        float ng = 1.f - 2.f / (__expf(2.f * pre) + 1.f);
        float hold = h32[er * 32 + c0 + 1];
        hnew1 = (1.f - zg) * ng + zg * hold;
        h32[er * 32 + c0 + 1] = hnew1;
      }
      size_t orow = ((size_t)t * BB + brow) * HH + j * 32 + c0;
      out[orow] = hnew0;
      out[orow + 1] = hnew1;
      uint32_t pk = (uint32_t)f2bf(hnew0) | ((uint32_t)f2bf(hnew1) << 16);
      __hip_atomic_store(&hb[(size_t)((t + 1) & 1) * 65536 + (((size_t)brow * HH + j * 32 + c0) >> 1)],
                         pk, __ATOMIC_RELAXED, __HIP_MEMORY_SCOPE_AGENT);
    }
    tgt += 32;
    gbar(ctr, tgt);
  }

  // final hidden: [1,B,H] appended after outputs
  if (tid < 256) {
    int brow = m * 16 + er, col = j * 32 + ecp * 2;
    size_t base = (size_t)TT * BB * HH + (size_t)brow * HH + col;
    out[base] = h32[er * 32 + ecp * 2];
    out[base + 1] = h32[er * 32 + ecp * 2 + 1];
  }
}

extern "C" void kernel_launch(void* const* d_in, const int* in_sizes, int n_in,
                              void* d_out, int out_size, void* d_ws, size_t ws_size,
                              hipStream_t stream) {
  const float* seq = (const float*)d_in[0];
  const float* word = (const float*)d_in[1];
  const float* inith = (const float*)d_in[2];
  const float* Wih = (const float*)d_in[3];
  const float* Whh = (const float*)d_in[4];
  const float* bih = (const float*)d_in[5];
  const float* bhh = (const float*)d_in[6];
  float* out = (float*)d_out;

  char* ws = (char*)d_ws;
  size_t off = 0;
  auto alloc = [&](size_t bytes) {
    void* p = ws + off;
    off += (bytes + 255) & ~(size_t)255;
    return p;
  };
  unsigned short* gxb = (unsigned short*)alloc((size_t)TT * BB * G3 * 2);  // 402.7 MB
  unsigned short* whhb = (unsigned short*)alloc((size_t)G3 * HH * 2);      // 6.3 MB
  float* wg = (float*)alloc((size_t)BB * G3 * 4);                          // 1.6 MB
  uint32_t* hb = (uint32_t*)alloc((size_t)2 * BB * HH * 2);                // 0.5 MB
  int* ctr = (int*)alloc(4096);

  hipMemsetAsync(ctr, 0, 4096, stream);
  k_cvt_whh<<<(G3 * HH / 2) / 256, 256, 0, stream>>>(Whh, (uint32_t*)whhb);
  k_wordgate<<<G3, 128, 0, stream>>>(word, Wih, bih, bhh, wg);
  k_gemm_gx<<<(TT * BB / 128) * (G3 / 128), 256, 0, stream>>>(seq, Wih, wg, gxb);
  k_scan<<<256, 384, 0, stream>>>(gxb, whhb, inith, bhh, hb, ctr, out);
}

// Round 2
// 2745.529 us; speedup vs baseline: 8.1730x; 1.2733x over previous
//
#include <hip/hip_runtime.h>
#include <hip/hip_bf16.h>
#include <stdint.h>

// Problem dims
#define TT 512
#define BB 128
#define ESEQ 768
#define CONDD 256
#define HH 1024
#define G3 3072

typedef __attribute__((ext_vector_type(4))) float f32x4;
typedef __attribute__((ext_vector_type(8))) short bf16x8;

__device__ __forceinline__ unsigned short f2bf(float f) {
  union { float f; uint32_t u; } v; v.f = f;
  uint32_t r = v.u + 0x7fffu + ((v.u >> 16) & 1u);
  return (unsigned short)(r >> 16);
}
__device__ __forceinline__ float bf2f(uint32_t b16) {
  union { uint32_t u; float f; } v; v.u = (b16 & 0xffffu) << 16;
  return v.f;
}

// async global->LDS, 16B per lane. LDS dest must be wave-uniform base (+lane*16 implicit).
__device__ __forceinline__ void gload_lds16(const unsigned short* g, unsigned short* l) {
  __builtin_amdgcn_global_load_lds(
      (const __attribute__((address_space(1))) unsigned int*)g,
      (__attribute__((address_space(3))) unsigned int*)l, 16, 0, 0);
}

// ---------------- fp32 -> bf16 pair converters ----------------
__global__ __launch_bounds__(256) void k_cvt_pairs(const float* __restrict__ w,
                                                   uint32_t* __restrict__ o) {
  int i = blockIdx.x * 256 + threadIdx.x;  // pair index
  const float2* s = (const float2*)w;
  float2 v = s[i];
  o[i] = (uint32_t)f2bf(v.x) | ((uint32_t)f2bf(v.y) << 16);
}

// W_ih[:, 256:1024] -> bf16 [3072][768]
__global__ __launch_bounds__(128) void k_cvt_wih(const float* __restrict__ Wih,
                                                 uint32_t* __restrict__ o) {
  int g = blockIdx.x;
  const float2* src = (const float2*)(Wih + (size_t)g * 1024 + CONDD);
  uint32_t* dst = o + (size_t)g * (ESEQ / 2);
#pragma unroll
  for (int k = 0; k < 3; k++) {
    int pc = threadIdx.x + k * 128;  // 384 pairs per row
    float2 v = src[pc];
    dst[pc] = (uint32_t)f2bf(v.x) | ((uint32_t)f2bf(v.y) << 16);
  }
}

// ---------------- wordgate[b,g] = word[b,:] . W_ih[g,:256] + b_ih[g] (+ b_hh r/z) --------
__global__ __launch_bounds__(128) void k_wordgate(const float* __restrict__ word,
                                                  const float* __restrict__ Wih,
                                                  const float* __restrict__ bih,
                                                  const float* __restrict__ bhh,
                                                  float* __restrict__ wg) {
  __shared__ float wrow[CONDD];
  int g = blockIdx.x;
  for (int e = threadIdx.x; e < CONDD; e += 128) wrow[e] = Wih[(size_t)g * 1024 + e];
  __syncthreads();
  int b = threadIdx.x;
  float bias = bih[g] + (g < 2048 ? bhh[g] : 0.f);  // b_hh new-gate part handled in scan
  const f32x4* wr4 = (const f32x4*)(word + (size_t)b * CONDD);
  const f32x4* wo4 = (const f32x4*)wrow;
  float s = 0.f;
#pragma unroll 8
  for (int e = 0; e < CONDD / 4; e++) {
    f32x4 a = wr4[e], c = wo4[e];
    s += a.x * c.x + a.y * c.y + a.z * c.z + a.w * c.w;
  }
  wg[(size_t)b * G3 + g] = s + bias;
}

// ---------------- gx GEMM v2 (m97 structure): bf16 inputs, global_load_lds staging -------
// [65536 x 768]bf16 * [3072 x 768]bf16^T -> bf16 gx. 128x128 tile, BK=64,
// 4 waves x (64x64 out via 4x4 of 16x16x32 MFMA). Linear LDS (required by
// global_load_lds), XCD-aware swizzle (nwg=12288 divisible by 8).
__global__ __launch_bounds__(256) void k_gemm_gx2(const unsigned short* __restrict__ seqb,
                                                  const unsigned short* __restrict__ wihb,
                                                  const float* __restrict__ wg,
                                                  unsigned short* __restrict__ gx) {
  __shared__ unsigned short lA[128 * 64];
  __shared__ unsigned short lB[128 * 64];
  int bx = blockIdx.x;
  int swz = (bx & 7) * (12288 / 8) + (bx >> 3);  // contiguous chunk per XCD
  int m0 = (swz / 24) * 128;
  int n0 = (swz % 24) * 128;
  int tid = threadIdx.x;
  int lane = tid & 63, w = tid >> 6;
  int mw = w & 1, nw = w >> 1;
  int fr = lane & 15, kq = lane >> 4;

  f32x4 acc[4][4];
#pragma unroll
  for (int i = 0; i < 4; i++)
#pragma unroll
    for (int j = 0; j < 4; j++) acc[i][j] = (f32x4){0.f, 0.f, 0.f, 0.f};

  int r = tid >> 3, c = tid & 7;  // 16B chunk (i>>3 row, i&7 chunk) for i = q*256+tid
  const unsigned short* ag = seqb + (size_t)(m0 + r) * ESEQ + c * 8;
  const unsigned short* bg = wihb + (size_t)(n0 + r) * ESEQ + c * 8;
  unsigned short* lAw = lA + (size_t)(w * 64) * 8;  // wave-uniform LDS base, +q*256*8 per round
  unsigned short* lBw = lB + (size_t)(w * 64) * 8;

  for (int kk = 0; kk < ESEQ / 64; kk++) {
#pragma unroll
    for (int q = 0; q < 4; q++) {
      gload_lds16(ag + (size_t)q * 32 * ESEQ + kk * 64, lAw + q * 2048);
      gload_lds16(bg + (size_t)q * 32 * ESEQ + kk * 64, lBw + q * 2048);
    }
    __syncthreads();
#pragma unroll
    for (int ks = 0; ks < 2; ks++) {
      bf16x8 af[4], bfr[4];
#pragma unroll
      for (int i = 0; i < 4; i++)
        af[i] = *(const bf16x8*)(lA + (mw * 64 + i * 16 + fr) * 64 + ks * 32 + kq * 8);
#pragma unroll
      for (int j = 0; j < 4; j++)
        bfr[j] = *(const bf16x8*)(lB + (nw * 64 + j * 16 + fr) * 64 + ks * 32 + kq * 8);
#pragma unroll
      for (int i = 0; i < 4; i++)
#pragma unroll
        for (int j = 0; j < 4; j++)
          acc[i][j] = __builtin_amdgcn_mfma_f32_16x16x32_bf16(af[i], bfr[j], acc[i][j], 0, 0, 0);
    }
    __syncthreads();
  }

  // epilogue: C[row][col] : col=lane&15, row=(lane>>4)*4+reg (m89/m91-verified)
#pragma unroll
  for (int i = 0; i < 4; i++) {
#pragma unroll
    for (int j = 0; j < 4; j++) {
      int col = n0 + nw * 64 + j * 16 + fr;
      int rbase = m0 + mw * 64 + i * 16 + kq * 4;
#pragma unroll
      for (int rr = 0; rr < 4; rr++) {
        int row = rbase + rr;
        float v = acc[i][j][rr] + wg[(size_t)(row & (BB - 1)) * G3 + col];
        gx[(size_t)row * G3 + col] = f2bf(v);
      }
    }
  }
}

// ---------------- gx GEMM v1 (fallback when workspace too small for bf16 copies) --------
__global__ __launch_bounds__(256) void k_gemm_gx(const float* __restrict__ seq,
                                                 const float* __restrict__ Wih,
                                                 const float* __restrict__ wg,
                                                 unsigned short* __restrict__ gx) {
  __shared__ unsigned short lA[128 * 72];
  __shared__ unsigned short lB[128 * 72];
  int bx = blockIdx.x;
  int m0 = (bx / 24) * 128;
  int n0 = (bx % 24) * 128;
  int tid = threadIdx.x;
  int lane = tid & 63, w = tid >> 6;
  int mw = w & 1, nw = w >> 1;
  int fr = lane & 15, kq = lane >> 4;

  f32x4 acc[4][4];
#pragma unroll
  for (int i = 0; i < 4; i++)
#pragma unroll
    for (int j = 0; j < 4; j++) acc[i][j] = (f32x4){0.f, 0.f, 0.f, 0.f};

  int r = tid >> 1, hf = tid & 1;
  const float* aptr = seq + (size_t)(m0 + r) * ESEQ + hf * 32;
  const float* bptr = Wih + (size_t)(n0 + r) * 1024 + CONDD + hf * 32;
  unsigned short* lAw = lA + r * 72 + hf * 32;
  unsigned short* lBw = lB + r * 72 + hf * 32;

  for (int kk = 0; kk < ESEQ / 64; kk++) {
#pragma unroll
    for (int q = 0; q < 4; q++) {
      f32x4 a0 = *(const f32x4*)(aptr + kk * 64 + q * 8);
      f32x4 a1 = *(const f32x4*)(aptr + kk * 64 + q * 8 + 4);
      f32x4 b0 = *(const f32x4*)(bptr + kk * 64 + q * 8);
      f32x4 b1 = *(const f32x4*)(bptr + kk * 64 + q * 8 + 4);
      union { bf16x8 v; unsigned short s[8]; } pa, pb;
      pa.s[0] = f2bf(a0.x); pa.s[1] = f2bf(a0.y); pa.s[2] = f2bf(a0.z); pa.s[3] = f2bf(a0.w);
      pa.s[4] = f2bf(a1.x); pa.s[5] = f2bf(a1.y); pa.s[6] = f2bf(a1.z); pa.s[7] = f2bf(a1.w);
      pb.s[0] = f2bf(b0.x); pb.s[1] = f2bf(b0.y); pb.s[2] = f2bf(b0.z); pb.s[3] = f2bf(b0.w);
      pb.s[4] = f2bf(b1.x); pb.s[5] = f2bf(b1.y); pb.s[6] = f2bf(b1.z); pb.s[7] = f2bf(b1.w);
      *(bf16x8*)(lAw + q * 8) = pa.v;
      *(bf16x8*)(lBw + q * 8) = pb.v;
    }
    __syncthreads();
#pragma unroll
    for (int ks = 0; ks < 2; ks++) {
      bf16x8 af[4], bfr[4];
#pragma unroll
      for (int i = 0; i < 4; i++)
        af[i] = *(const bf16x8*)(lA + (mw * 64 + i * 16 + fr) * 72 + ks * 32 + kq * 8);
#pragma unroll
      for (int j = 0; j < 4; j++)
        bfr[j] = *(const bf16x8*)(lB + (nw * 64 + j * 16 + fr) * 72 + ks * 32 + kq * 8);
#pragma unroll
      for (int i = 0; i < 4; i++)
#pragma unroll
        for (int j = 0; j < 4; j++)
          acc[i][j] = __builtin_amdgcn_mfma_f32_16x16x32_bf16(af[i], bfr[j], acc[i][j], 0, 0, 0);
    }
    __syncthreads();
  }

#pragma unroll
  for (int i = 0; i < 4; i++) {
#pragma unroll
    for (int j = 0; j < 4; j++) {
      int col = n0 + nw * 64 + j * 16 + fr;
      int rbase = m0 + mw * 64 + i * 16 + kq * 4;
#pragma unroll
      for (int rr = 0; rr < 4; rr++) {
        int row = rbase + rr;
        float v = acc[i][j][rr] + wg[(size_t)(row & (BB - 1)) * G3 + col];
        gx[(size_t)row * G3 + col] = f2bf(v);
      }
    }
  }
}

// ---------------- persistent scan kernel ----------------
// 256 blocks = 8 m-groups (16 batch rows each) x 32 j-chunks (32 h-cols each).
// All cross-block data moves via agent-scope ATOMICS (sc1, MALL-direct) — no
// acquire/release fences (those lower to L2 invalidate/writeback storms).
// Ordering: this block's sc1 stores drained (vmcnt 0) before the counter add.
// Arrive/wait split: the fp32 out[] stores are issued BETWEEN arrive and wait
// so their HBM ack overlaps the poll instead of sitting in the drain.
__device__ __forceinline__ void gbar_arrive(int* ctr) {
  asm volatile("s_waitcnt vmcnt(0)" ::: "memory");
  __syncthreads();  // all waves drained before t0 signals
  if (threadIdx.x == 0)
    __hip_atomic_fetch_add(ctr, 1, __ATOMIC_RELAXED, __HIP_MEMORY_SCOPE_AGENT);
}
__device__ __forceinline__ void gbar_wait(int* ctr, int target) {
  if (threadIdx.x == 0) {
    while (__hip_atomic_load(ctr, __ATOMIC_RELAXED, __HIP_MEMORY_SCOPE_AGENT) < target) {
      __builtin_amdgcn_s_sleep(1);
    }
  }
  __syncthreads();
}

__global__ __launch_bounds__(384, 2) void k_scan(const unsigned short* __restrict__ gx,
                                                 const unsigned short* __restrict__ whhb,
                                                 const float* __restrict__ inith,
                                                 const float* __restrict__ bhh,
                                                 uint32_t* __restrict__ hb,  // [2][65536] bf16-pairs
                                                 int* __restrict__ counters,
                                                 float* __restrict__ out) {
  __shared__ unsigned short lh[16 * 1032];  // A tile, padded rows (2064B stride)
  __shared__ float ghs[3 * 16 * 32];
  __shared__ float h32[16 * 32];

  int bx = blockIdx.x;
  int m = bx & 7, j = bx >> 3;
  int tid = threadIdx.x;
  int lane = tid & 63, w = tid >> 6;
  int gate = w >> 1, nt = w & 1;
  int fr = lane & 15, kq = lane >> 4;
  int* ctr = counters + m * 32;

  // W_hh fragments for this wave's 16 gh-columns, all K=1024, in registers.
  bf16x8 bw[32];
  {
    const bf16x8* wp =
        (const bf16x8*)(whhb + ((size_t)(gate * 1024 + j * 32 + nt * 16 + fr)) * 1024 + kq * 8);
#pragma unroll
    for (int ks = 0; ks < 32; ks++) bw[ks] = wp[ks * 4];
  }

  int er = tid >> 4, ecp = tid & 15;  // elementwise mapping (tid<256): row er, col-pair ecp
  float bhn0 = 0.f, bhn1 = 0.f;
  if (tid < 256) {
    bhn0 = bhh[2048 + j * 32 + ecp * 2];
    bhn1 = bhh[2048 + j * 32 + ecp * 2 + 1];
  }

  // init h state (fp32 slice in LDS; bf16 copy to global buf0)
  if (tid < 256) {
    int brow = m * 16 + er, col = j * 32 + ecp * 2;
    float a = inith[(size_t)brow * HH + col];
    float b = inith[(size_t)brow * HH + col + 1];
    h32[er * 32 + ecp * 2] = a;
    h32[er * 32 + ecp * 2 + 1] = b;
    uint32_t pk = (uint32_t)f2bf(a) | ((uint32_t)f2bf(b) << 16);
    __hip_atomic_store(&hb[((size_t)brow * HH + col) >> 1], pk, __ATOMIC_RELAXED,
                       __HIP_MEMORY_SCOPE_AGENT);
  }
  gbar_arrive(ctr);
  gbar_wait(ctr, 32);
  int tgt = 32;

  for (int t = 0; t < TT; t++) {
    // prefetch gx for this step (t-dependent only; overlaps with h staging + MFMA)
    uint32_t xru = 0, xzu = 0, xnu = 0;
    if (tid < 256) {
      int brow = m * 16 + er;
      const uint32_t* gxp = (const uint32_t*)(gx + ((size_t)t * BB + brow) * G3 + j * 32);
      xru = gxp[ecp];
      xzu = gxp[512 + ecp];
      xnu = gxp[1024 + ecp];
    }

    // stage h rows [m*16, m*16+16) from buf (t&1): 4096 x 8B, agent-scope (cross-XCD fresh)
    {
      const uint64_t* src = (const uint64_t*)hb + (size_t)(t & 1) * 32768 + (size_t)m * 4096;
      uint64_t tmp[11];
#pragma unroll
      for (int q = 0; q < 11; q++) {
        int i = tid + q * 384;
        if (i < 4096) tmp[q] = __hip_atomic_load(src + i, __ATOMIC_RELAXED, __HIP_MEMORY_SCOPE_AGENT);
      }
#pragma unroll
      for (int q = 0; q < 11; q++) {
        int i = tid + q * 384;
        if (i < 4096) {
          int rr = i >> 8, c4 = i & 255;
          *(uint64_t*)(lh + rr * 1032 + c4 * 4) = tmp[q];
        }
      }
    }
    __syncthreads();

    // gh tile: 16(batch) x 16(cols) for this wave's gate
    f32x4 acc = (f32x4){0.f, 0.f, 0.f, 0.f};
#pragma unroll
    for (int ks = 0; ks < 32; ks++) {
      bf16x8 af = *(const bf16x8*)(lh + fr * 1032 + kq * 8 + ks * 32);
      acc = __builtin_amdgcn_mfma_f32_16x16x32_bf16(af, bw[ks], acc, 0, 0, 0);
    }
#pragma unroll
    for (int rr = 0; rr < 4; rr++)
      ghs[gate * 512 + (kq * 4 + rr) * 32 + nt * 16 + fr] = acc[rr];
    __syncthreads();

    // gates + state update (256 workers: 16 rows x 16 col-pairs)
    float hnew0 = 0.f, hnew1 = 0.f;
    size_t orow = 0;
    if (tid < 256) {
      int brow = m * 16 + er;
      int c0 = ecp * 2;
      {
        float xr = bf2f(xru), xz = bf2f(xzu), xn = bf2f(xnu);
        float hr = ghs[0 * 512 + er * 32 + c0];
        float hz = ghs[1 * 512 + er * 32 + c0];
        float hn = ghs[2 * 512 + er * 32 + c0] + bhn0;
        float rg = 1.f / (1.f + __expf(-(xr + hr)));
        float zg = 1.f / (1.f + __expf(-(xz + hz)));
        float pre = xn + rg * hn;
        float ng = 1.f - 2.f / (__expf(2.f * pre) + 1.f);
        float hold = h32[er * 32 + c0];
        hnew0 = (1.f - zg) * ng + zg * hold;
        h32[er * 32 + c0] = hnew0;
      }
      {
        float xr = bf2f(xru >> 16), xz = bf2f(xzu >> 16), xn = bf2f(xnu >> 16);
        float hr = ghs[0 * 512 + er * 32 + c0 + 1];
        float hz = ghs[1 * 512 + er * 32 + c0 + 1];
        float hn = ghs[2 * 512 + er * 32 + c0 + 1] + bhn1;
        float rg = 1.f / (1.f + __expf(-(xr + hr)));
        float zg = 1.f / (1.f + __expf(-(xz + hz)));
        float pre = xn + rg * hn;
        float ng = 1.f - 2.f / (__expf(2.f * pre) + 1.f);
        float hold = h32[er * 32 + c0 + 1];
        hnew1 = (1.f - zg) * ng + zg * hold;
        h32[er * 32 + c0 + 1] = hnew1;
      }
      orow = ((size_t)t * BB + brow) * HH + j * 32 + c0;
      uint32_t pk = (uint32_t)f2bf(hnew0) | ((uint32_t)f2bf(hnew1) << 16);
      __hip_atomic_store(&hb[(size_t)((t + 1) & 1) * 65536 + (((size_t)brow * HH + j * 32 + c0) >> 1)],
                         pk, __ATOMIC_RELAXED, __HIP_MEMORY_SCOPE_AGENT);
    }
    tgt += 32;
    gbar_arrive(ctr);  // drains hb stores (out stores not yet issued -> shorter critical chain)
    if (tid < 256) {
      out[orow] = hnew0;  // overlaps with poll; drains at next step's arrive
      out[orow + 1] = hnew1;
    }
    gbar_wait(ctr, tgt);
  }

  // final hidden: [1,B,H] appended after outputs
  if (tid < 256) {
    int brow = m * 16 + er, col = j * 32 + ecp * 2;
    size_t base = (size_t)TT * BB * HH + (size_t)brow * HH + col;
    out[base] = h32[er * 32 + ecp * 2];
    out[base + 1] = h32[er * 32 + ecp * 2 + 1];
  }
}

extern "C" void kernel_launch(void* const* d_in, const int* in_sizes, int n_in,
                              void* d_out, int out_size, void* d_ws, size_t ws_size,
                              hipStream_t stream) {
  const float* seq = (const float*)d_in[0];
  const float* word = (const float*)d_in[1];
  const float* inith = (const float*)d_in[2];
  const float* Wih = (const float*)d_in[3];
  const float* Whh = (const float*)d_in[4];
  const float* bih = (const float*)d_in[5];
  const float* bhh = (const float*)d_in[6];
  float* out = (float*)d_out;

  char* ws = (char*)d_ws;
  size_t off = 0;
  auto alloc = [&](size_t bytes) {
    void* p = ws + off;
    off += (bytes + 255) & ~(size_t)255;
    return p;
  };
  unsigned short* gxb = (unsigned short*)alloc((size_t)TT * BB * G3 * 2);  // 402.7 MB
  unsigned short* whhb = (unsigned short*)alloc((size_t)G3 * HH * 2);      // 6.3 MB
  float* wg = (float*)alloc((size_t)BB * G3 * 4);                          // 1.6 MB
  uint32_t* hb = (uint32_t*)alloc((size_t)2 * BB * HH * 2);                // 0.5 MB
  int* ctr = (int*)alloc(4096);

  // bf16 operand copies for the fast GEMM path (gated on workspace size)
  size_t off_base = off;
  unsigned short* seqb = (unsigned short*)alloc((size_t)TT * BB * ESEQ * 2);  // 100.7 MB
  unsigned short* wihb = (unsigned short*)alloc((size_t)G3 * ESEQ * 2);       // 4.7 MB
  bool fast_gemm = (off <= ws_size);
  if (!fast_gemm) off = off_base;

  hipMemsetAsync(ctr, 0, 4096, stream);
  k_cvt_pairs<<<(G3 * HH / 2) / 256, 256, 0, stream>>>(Whh, (uint32_t*)whhb);
  k_wordgate<<<G3, 128, 0, stream>>>(word, Wih, bih, bhh, wg);
  if (fast_gemm) {
    k_cvt_pairs<<<((size_t)TT * BB * ESEQ / 2) / 256, 256, 0, stream>>>(seq, (uint32_t*)seqb);
    k_cvt_wih<<<G3, 128, 0, stream>>>(Wih, (uint32_t*)wihb);
    k_gemm_gx2<<<(TT * BB / 128) * (G3 / 128), 256, 0, stream>>>(seqb, wihb, wg, gxb);
  } else {
    k_gemm_gx<<<(TT * BB / 128) * (G3 / 128), 256, 0, stream>>>(seq, Wih, wg, gxb);
  }
  k_scan<<<256, 384, 0, stream>>>(gxb, whhb, inith, bhh, hb, ctr, out);
}